// Round 13
// baseline (377.272 us; speedup 1.0000x reference)
//
#include <hip/hip_runtime.h>
#include <hip/hip_bf16.h>
#include <stdint.h>

#define N_PTS   8192
#define D       256
#define N_E     8192
#define BETA    0.25f
#define EPS_1   1.0000001f   // 1 + 1e-7 (rounds to 1+ulp in f32, same as jnp)

typedef unsigned long long u64;
typedef __attribute__((ext_vector_type(8))) short bf16x8;   // 8 bf16 = 4 VGPR
typedef __attribute__((ext_vector_type(8))) short short8;
typedef __attribute__((ext_vector_type(4))) float f32x4;

// ---- workspace layout (bytes) ----
// Fragment-linear bf16 arrays for 16x16x32 MFMA (R2-R4 proven layout):
// element (p,k) of an 8192x256 matrix lives at
//   blk = (p>>4)*8 + (k>>5);  l = ((k>>3)&3)*16 + (p&15);  j = k&7
//   idx = blk*512 + l*8 + j
// Each 16x32 fragment is a contiguous 1KB block in lane-major order:
// global_load_lds(uniform base + lane*16) and ds_read_b128(lane*16) are both
// perfectly linear -> zero bank conflicts (verified R3-R12: conflicts = 0).
#define WS_KEYS    0
#define WS_COUNTS  (N_PTS * 8)                   // 64 KB
#define WS_LOSS    (WS_COUNTS + N_E * 4)         // +32 KB
#define WS_RB_DONE (WS_LOSS + 16)                // 64 x u32
#define WS_GDONE   (WS_RB_DONE + 64 * 4)
#define WS_AHI     (1 << 20)                     // 1 MB-aligned
#define WS_ALO     (WS_AHI + N_PTS * D * 2)
#define WS_BHI     (WS_ALO + N_PTS * D * 2)
#define WS_BLO     (WS_BHI + N_E * D * 2)        // total ~17 MB

__device__ __forceinline__ short f2bf(float x) {
    __hip_bfloat16 h = __float2bfloat16(x);      // RTN-even
    return *reinterpret_cast<short*>(&h);
}
__device__ __forceinline__ float bf2f(short s) {
    __hip_bfloat16 h = *reinterpret_cast<__hip_bfloat16*>(&s);
    return __bfloat162float(h);
}

#define GLOAD16(gp, lp) __builtin_amdgcn_global_load_lds(                      \
    (const __attribute__((address_space(1))) void*)(gp),                       \
    (__attribute__((address_space(3))) void*)(lp), 16, 0, 0)

// DPP f32 min step: x = min(x, x[dpp-perm(lane)]); pure VALU, no DS pipe.
// (validated on HW in R10/R12)
#define DPP_MIN(x, ctrl)                                                       \
    x = fminf(x, __int_as_float(__builtin_amdgcn_update_dpp(                   \
            __float_as_int(x), __float_as_int(x), (ctrl), 0xF, 0xF, true)))

// ------- init + split f32 -> bf16 hi/lo, fragment-linear layout -------------
__global__ __launch_bounds__(256) void k_prep(
    const float* __restrict__ u, const float* __restrict__ cb,
    short* __restrict__ Ahi, short* __restrict__ Alo,
    short* __restrict__ Bhi, short* __restrict__ Blo,
    u64* __restrict__ keys, float* __restrict__ counts,
    double* __restrict__ loss_sum, unsigned* __restrict__ rb_done,
    unsigned* __restrict__ gdone)
{
    const int tid = blockIdx.x * 256 + threadIdx.x;   // 0 .. 262143
    if (tid < N_E)   counts[tid] = 0.f;
    if (tid < N_PTS) keys[tid] = ~0ULL;
    if (tid == 0)    *loss_sum = 0.0;
    if (tid < 64)    rb_done[tid] = 0u;
    if (tid == 64)   *gdone = 0u;

    const int blk = tid >> 6;            // = (p>>4)*8 + (k>>5)
    const int l   = tid & 63;
    const int s   = blk >> 3, c = blk & 7;
    const int p   = s * 16 + (l & 15);
    const int k   = c * 32 + (l >> 4) * 8;
    const size_t gin  = (size_t)p * D + k;
    const size_t gout = (size_t)tid * 8;

    float v[8];
    short8 h8, l8;

    *(float4*)&v[0] = *(const float4*)&u[gin];
    *(float4*)&v[4] = *(const float4*)&u[gin + 4];
    if (k == 0) v[0] = -v[0];            // Minkowski sign fold on time comp
    #pragma unroll
    for (int j = 0; j < 8; ++j) {
        h8[j] = f2bf(v[j]);
        l8[j] = f2bf(v[j] - bf2f(h8[j]));
    }
    *(short8*)&Ahi[gout] = h8;
    *(short8*)&Alo[gout] = l8;

    *(float4*)&v[0] = *(const float4*)&cb[gin];
    *(float4*)&v[4] = *(const float4*)&cb[gin + 4];
    #pragma unroll
    for (int j = 0; j < 8; ++j) {
        h8[j] = f2bf(v[j]);
        l8[j] = f2bf(v[j] - bf2f(h8[j]));
    }
    *(short8*)&Bhi[gout] = h8;
    *(short8*)&Blo[gout] = l8;
}

// ---------------- fused MFMA argmin + gather + finalize ---------------------
// split-bf16: a.b = ahi.bhi + ahi.blo + alo.bhi  (err ~2^-18 rel, safe margin)
// EXACT R12 loop (measured optimum: 102 us argmin, FETCH 37 MB, 0 conflicts):
// 128x128 tile, 4 waves 2x2, 16x16x32 MFMA, 32 KB single-buffer LDS,
// 2 barriers/K-step, launch_bounds(256,4), natural block order, DPP epilogue.
// NEW (R13): gather + finalize fused in via two-level last-block handshake:
//   level 1: 64 cbk-blocks per rb; the 64th (rb_done) gathers z_q/counts/loss
//            for its 128 rows (keys final; read via identity atomicMin RMW).
//   level 2: 64 rb-finishers; the 64th (gdone) computes entropy/e_mean/loss.
// All cross-block reads are device-scope atomic RMWs -> no coherence hazards.
#define BMM 128
#define BNN 128
#define NKS (D / 32)         // 8 K-steps of 32

__global__ __launch_bounds__(256, 4) void k_argmin_mfma(
    const short* __restrict__ Ahi, const short* __restrict__ Alo,
    const short* __restrict__ Bhi, const short* __restrict__ Blo,
    u64* __restrict__ keys,
    const float* __restrict__ u, const float* __restrict__ cb,
    float* __restrict__ out, float* __restrict__ counts,
    double* __restrict__ loss_sum, unsigned* __restrict__ rb_done,
    unsigned* __restrict__ gdone)
{
    __shared__ short sm[4][8 * 512];     // Ahi,Alo,Bhi,Blo: 8 KB each = 32 KB
    __shared__ int   sflag;

    const int t   = threadIdx.x;
    const int w   = t >> 6;              // wave 0..3
    const int l   = t & 63;
    // natural order (R4-verified locality: FETCH 37 MB, L2-resident panels)
    const int rb  = blockIdx.x >> 6;     // 64 row-blocks (points)
    const int cbk = blockIdx.x & 63;     // 64 col-blocks (codes)
    const int r0  = rb * BMM, c0 = cbk * BNN;
    const int wr  = w >> 1, wc = w & 1;  // 2x2 wave grid, 64x64 each

    // staging: wave w owns one array; 8 fragment-blocks of 1KB per K-step
    const short* gsrc = (w == 0) ? Ahi : (w == 1) ? Alo : (w == 2) ? Bhi : Blo;
    short* ldst = sm[w];
    const int s0 = ((w < 2) ? rb : cbk) * 8;   // first 16-row slice index

    f32x4 acc[4][4];
    #pragma unroll
    for (int i = 0; i < 4; ++i)
        #pragma unroll
        for (int j = 0; j < 4; ++j) acc[i][j] = (f32x4){0.f, 0.f, 0.f, 0.f};

    for (int kk = 0; kk < NKS; ++kk) {
        __syncthreads();                 // prev compute done before overwrite
        #pragma unroll
        for (int i = 0; i < 8; ++i)
            GLOAD16(gsrc + (size_t)((s0 + i) * 8 + kk) * 512 + l * 8,
                    ldst + i * 512);
        __syncthreads();                 // drains vmcnt: tiles ready

        bf16x8 ah[4], al[4], bh[4], bl[4];
        #pragma unroll
        for (int f = 0; f < 4; ++f) {
            ah[f] = *(const bf16x8*)&sm[0][(wr * 4 + f) * 512 + l * 8];
            al[f] = *(const bf16x8*)&sm[1][(wr * 4 + f) * 512 + l * 8];
            bh[f] = *(const bf16x8*)&sm[2][(wc * 4 + f) * 512 + l * 8];
            bl[f] = *(const bf16x8*)&sm[3][(wc * 4 + f) * 512 + l * 8];
        }
        #pragma unroll
        for (int mf = 0; mf < 4; ++mf)
            #pragma unroll
            for (int nf = 0; nf < 4; ++nf) {
                acc[mf][nf] = __builtin_amdgcn_mfma_f32_16x16x32_bf16(
                    ah[mf], bh[nf], acc[mf][nf], 0, 0, 0);
                acc[mf][nf] = __builtin_amdgcn_mfma_f32_16x16x32_bf16(
                    ah[mf], bl[nf], acc[mf][nf], 0, 0, 0);
                acc[mf][nf] = __builtin_amdgcn_mfma_f32_16x16x32_bf16(
                    al[mf], bh[nf], acc[mf][nf], 0, 0, 0);
            }
    }

    // ---- DPP epilogue: per-row argmin, ZERO DS-pipe ops (R10/R12) ----
    // C/D layout (m89-verified): col = lane&15, row = (lane>>4)*4 + reg.
    const int g  = l >> 4;
    const int cc = l & 15;
    #pragma unroll
    for (int mf = 0; mf < 4; ++mf) {
        #pragma unroll
        for (int r = 0; r < 4; ++r) {
            float mm = fmaxf(-acc[mf][0][r], EPS_1);
            unsigned code = (unsigned)(c0 + wc * 64 + cc);
            #pragma unroll
            for (int nf = 1; nf < 4; ++nf) {
                float mv = fmaxf(-acc[mf][nf][r], EPS_1);
                if (mv < mm) { mm = mv; code = (unsigned)(c0 + wc * 64 + nf * 16 + cc); }
            }
            float mv = mm;
            DPP_MIN(mv, 0xB1);           // quad_perm xor1
            DPP_MIN(mv, 0x4E);           // quad_perm xor2
            DPP_MIN(mv, 0x141);          // row_half_mirror (8-group reversal)
            DPP_MIN(mv, 0x140);          // row_mirror (16-group reversal)
            if (mm == mv) {
                const int row = r0 + wr * 64 + mf * 16 + g * 4 + r;
                u64 key = ((u64)__float_as_uint(mm) << 32) | code;
                atomicMin(&keys[row], key);
            }
        }
    }

    // ---- level-1 handshake: last cbk-block for this rb does the gather ----
    __syncthreads();                     // drain all key atomics (vm+barrier)
    if (t == 0) {
        __threadfence();                 // release our mins
        sflag = (atomicAdd(&rb_done[rb], 1u) == 63u);
    }
    __syncthreads();
    if (!sflag) return;
    __threadfence();                     // acquire others' mins

    // keys for rows r0..r0+127 are final: read via identity atomicMin RMW
    u64* smk = (u64*)&sm[0][0];          // reuse LDS (1 KB)
    if (t < BMM)
        smk[t] = atomicMin(&keys[r0 + t], ~0ULL);
    __syncthreads();

    // gather: wave w handles rows w*32 .. w*32+31 (full 256-elem rows)
    float* zq = out + 1;
    float fsum = 0.f;
    for (int rr = 0; rr < 32; ++rr) {
        const int lrow = w * 32 + rr;
        const int row  = r0 + lrow;
        const int idx  = (int)(unsigned)(smk[lrow] & 0xffffffffULL);
        float4 uv = *(const float4*)&u[(size_t)row * D + l * 4];
        float4 cv = *(const float4*)&cb[(size_t)idx * D + l * 4];
        if (l == 0) uv.x = -uv.x;        // Lorentzian sign
        float partial = uv.x * cv.x + uv.y * cv.y + uv.z * cv.z + uv.w * cv.w;
        *(float4*)&zq[(size_t)row * D + l * 4] = cv;
        #pragma unroll
        for (int s = 32; s >= 1; s >>= 1)
            partial += __shfl_xor(partial, s);
        if (l == 0) {
            fsum += acoshf(fmaxf(-partial, EPS_1));
            atomicAdd(&counts[idx], 1.f);
        }
    }
    if (l == 0) atomicAdd(loss_sum, (double)fsum);

    // ---- level-2 handshake: last rb-finisher computes the scalars ----
    __syncthreads();                     // drain gather atomics
    if (t == 0) {
        __threadfence();
        sflag = (atomicAdd(gdone, 1u) == 63u);
    }
    __syncthreads();
    if (!sflag) return;
    __threadfence();

    // finalize: entropy / perplexity / e_mean / loss (counts via RMW reads)
    float* red = (float*)&sm[1][0];      // 1 KB scratch, disjoint from smk use
    const int OFF_P = 1 + N_PTS * D;
    float ent = 0.f;
    for (int i = t; i < N_E; i += 256) {
        float cv_ = atomicAdd(&counts[i], 0.f);   // device-coherent read
        float e = cv_ * (1.0f / N_PTS);
        out[OFF_P + 2 + i] = e;
        ent -= e * logf(e + 1e-10f);
    }
    red[t] = ent;
    __syncthreads();
    for (int s = 128; s > 0; s >>= 1) {
        if (t < s) red[t] += red[t + s];
        __syncthreads();
    }
    if (t == 0) {
        float entropy = red[0];
        double ls = atomicAdd(loss_sum, 0.0);     // device-coherent read
        out[0]         = (1.0f + BETA) * (float)(ls / (double)N_PTS);
        out[OFF_P]     = expf(entropy);
        out[OFF_P + 1] = entropy;
    }
}

// ---------------- launch ----------------
extern "C" void kernel_launch(void* const* d_in, const int* in_sizes, int n_in,
                              void* d_out, int out_size, void* d_ws, size_t ws_size,
                              hipStream_t stream)
{
    const float* u  = (const float*)d_in[0];
    const float* cb = (const float*)d_in[1];
    float* out = (float*)d_out;
    char* ws = (char*)d_ws;

    u64*      keys     = (u64*)(ws + WS_KEYS);
    float*    counts   = (float*)(ws + WS_COUNTS);
    double*   loss_sum = (double*)(ws + WS_LOSS);
    unsigned* rb_done  = (unsigned*)(ws + WS_RB_DONE);
    unsigned* gdone    = (unsigned*)(ws + WS_GDONE);
    short*    Ahi = (short*)(ws + WS_AHI);
    short*    Alo = (short*)(ws + WS_ALO);
    short*    Bhi = (short*)(ws + WS_BHI);
    short*    Blo = (short*)(ws + WS_BLO);

    k_prep<<<N_PTS * D / 8 / 256, 256, 0, stream>>>(
        u, cb, Ahi, Alo, Bhi, Blo, keys, counts, loss_sum, rb_done, gdone);
    k_argmin_mfma<<<(N_PTS / BMM) * (N_E / BNN), 256, 0, stream>>>(
        Ahi, Alo, Bhi, Blo, keys, u, cb, out, counts, loss_sum, rb_done, gdone);
}

// Round 14
// 185.873 us; speedup vs baseline: 2.0297x; 2.0297x over previous
//
#include <hip/hip_runtime.h>
#include <hip/hip_bf16.h>
#include <stdint.h>

#define N_PTS   8192
#define D       256
#define N_E     8192
#define BETA    0.25f
#define EPS_1   1.0000001f   // 1 + 1e-7 (rounds to 1+ulp in f32, same as jnp)

typedef unsigned long long u64;
typedef __attribute__((ext_vector_type(8))) short bf16x8;   // 8 bf16 = 4 VGPR
typedef __attribute__((ext_vector_type(8))) short short8;
typedef __attribute__((ext_vector_type(4))) float f32x4;

// ---- workspace layout (bytes) ----
// Fragment-linear bf16 arrays for 16x16x32 MFMA (R2-R4 proven layout):
// element (p,k) of an 8192x256 matrix lives at
//   blk = (p>>4)*8 + (k>>5);  l = ((k>>3)&3)*16 + (p&15);  j = k&7
//   idx = blk*512 + l*8 + j
// Each 16x32 fragment is a contiguous 1KB block in lane-major order:
// global_load_lds(uniform base + lane*16) and ds_read_b128(lane*16) are both
// perfectly linear -> zero bank conflicts (verified R3-R13: conflicts = 0).
#define WS_KEYS    0
#define WS_COUNTS  (N_PTS * 8)                   // 64 KB
#define WS_LOSS    (WS_COUNTS + N_E * 4)         // +32 KB
#define WS_RB_DONE (WS_LOSS + 16)                // 64 x u32
#define WS_GDONE   (WS_RB_DONE + 64 * 4)
#define WS_AHI     (1 << 20)                     // 1 MB-aligned
#define WS_ALO     (WS_AHI + N_PTS * D * 2)
#define WS_BHI     (WS_ALO + N_PTS * D * 2)
#define WS_BLO     (WS_BHI + N_E * D * 2)        // total ~17 MB

__device__ __forceinline__ short f2bf(float x) {
    __hip_bfloat16 h = __float2bfloat16(x);      // RTN-even
    return *reinterpret_cast<short*>(&h);
}
__device__ __forceinline__ float bf2f(short s) {
    __hip_bfloat16 h = *reinterpret_cast<__hip_bfloat16*>(&s);
    return __bfloat162float(h);
}

#define GLOAD16(gp, lp) __builtin_amdgcn_global_load_lds(                      \
    (const __attribute__((address_space(1))) void*)(gp),                       \
    (__attribute__((address_space(3))) void*)(lp), 16, 0, 0)

// DPP f32 min step: x = min(x, x[dpp-perm(lane)]); pure VALU, no DS pipe.
// (validated on HW in R10/R12)
#define DPP_MIN(x, ctrl)                                                       \
    x = fminf(x, __int_as_float(__builtin_amdgcn_update_dpp(                   \
            __float_as_int(x), __float_as_int(x), (ctrl), 0xF, 0xF, true)))

// ------- init + split f32 -> bf16 hi/lo, fragment-linear layout -------------
__global__ __launch_bounds__(256) void k_prep(
    const float* __restrict__ u, const float* __restrict__ cb,
    short* __restrict__ Ahi, short* __restrict__ Alo,
    short* __restrict__ Bhi, short* __restrict__ Blo,
    u64* __restrict__ keys, float* __restrict__ counts,
    double* __restrict__ loss_sum, unsigned* __restrict__ rb_done,
    unsigned* __restrict__ gdone)
{
    const int tid = blockIdx.x * 256 + threadIdx.x;   // 0 .. 262143
    if (tid < N_E)   counts[tid] = 0.f;
    if (tid < N_PTS) keys[tid] = ~0ULL;
    if (tid == 0)    *loss_sum = 0.0;
    if (tid < 64)    rb_done[tid] = 0u;
    if (tid == 64)   *gdone = 0u;

    const int blk = tid >> 6;            // = (p>>4)*8 + (k>>5)
    const int l   = tid & 63;
    const int s   = blk >> 3, c = blk & 7;
    const int p   = s * 16 + (l & 15);
    const int k   = c * 32 + (l >> 4) * 8;
    const size_t gin  = (size_t)p * D + k;
    const size_t gout = (size_t)tid * 8;

    float v[8];
    short8 h8, l8;

    *(float4*)&v[0] = *(const float4*)&u[gin];
    *(float4*)&v[4] = *(const float4*)&u[gin + 4];
    if (k == 0) v[0] = -v[0];            // Minkowski sign fold on time comp
    #pragma unroll
    for (int j = 0; j < 8; ++j) {
        h8[j] = f2bf(v[j]);
        l8[j] = f2bf(v[j] - bf2f(h8[j]));
    }
    *(short8*)&Ahi[gout] = h8;
    *(short8*)&Alo[gout] = l8;

    *(float4*)&v[0] = *(const float4*)&cb[gin];
    *(float4*)&v[4] = *(const float4*)&cb[gin + 4];
    #pragma unroll
    for (int j = 0; j < 8; ++j) {
        h8[j] = f2bf(v[j]);
        l8[j] = f2bf(v[j] - bf2f(h8[j]));
    }
    *(short8*)&Bhi[gout] = h8;
    *(short8*)&Blo[gout] = l8;
}

// ---------------- fused MFMA argmin + gather + finalize ---------------------
// split-bf16: a.b = ahi.bhi + ahi.blo + alo.bhi  (err ~2^-18 rel, safe margin)
// EXACT R12 loop (measured optimum: 102 us argmin, FETCH 37 MB, 0 conflicts).
// R14 vs R13 (384 us): ALL __threadfence() REMOVED -- the fence's buffer_wbl2
// forced 8192 L2 writeback storms (+46 MB HBM writes, L2 stalls for every
// CU). Fences are unnecessary: all cross-block data (keys/counts/loss/flags)
// is accessed ONLY via device-scope atomics (L2-coherent, L1-bypassing), and
// __syncthreads drains vmcnt(0) before each signal atomic issues, so a
// block's data atomics are acked in L2 before its flag increment can land.
// sflag overlaid into sm (LDS stays exactly 32768 -> 4 blocks/CU preserved;
// R13's 33280 crossed an alloc-granularity boundary, occupancy 37->23%).
#define BMM 128
#define BNN 128
#define NKS (D / 32)         // 8 K-steps of 32

__global__ __launch_bounds__(256, 4) void k_argmin_mfma(
    const short* __restrict__ Ahi, const short* __restrict__ Alo,
    const short* __restrict__ Bhi, const short* __restrict__ Blo,
    u64* __restrict__ keys,
    const float* __restrict__ u, const float* __restrict__ cb,
    float* __restrict__ out, float* __restrict__ counts,
    double* __restrict__ loss_sum, unsigned* __restrict__ rb_done,
    unsigned* __restrict__ gdone)
{
    __shared__ short sm[4][8 * 512];     // Ahi,Alo,Bhi,Blo: 8 KB each = 32 KB

    const int t   = threadIdx.x;
    const int w   = t >> 6;              // wave 0..3
    const int l   = t & 63;
    // natural order (R4-verified locality: FETCH 37 MB, L2-resident panels)
    const int rb  = blockIdx.x >> 6;     // 64 row-blocks (points)
    const int cbk = blockIdx.x & 63;     // 64 col-blocks (codes)
    const int r0  = rb * BMM, c0 = cbk * BNN;
    const int wr  = w >> 1, wc = w & 1;  // 2x2 wave grid, 64x64 each

    // staging: wave w owns one array; 8 fragment-blocks of 1KB per K-step
    const short* gsrc = (w == 0) ? Ahi : (w == 1) ? Alo : (w == 2) ? Bhi : Blo;
    short* ldst = sm[w];
    const int s0 = ((w < 2) ? rb : cbk) * 8;   // first 16-row slice index

    f32x4 acc[4][4];
    #pragma unroll
    for (int i = 0; i < 4; ++i)
        #pragma unroll
        for (int j = 0; j < 4; ++j) acc[i][j] = (f32x4){0.f, 0.f, 0.f, 0.f};

    for (int kk = 0; kk < NKS; ++kk) {
        __syncthreads();                 // prev compute done before overwrite
        #pragma unroll
        for (int i = 0; i < 8; ++i)
            GLOAD16(gsrc + (size_t)((s0 + i) * 8 + kk) * 512 + l * 8,
                    ldst + i * 512);
        __syncthreads();                 // drains vmcnt: tiles ready

        bf16x8 ah[4], al[4], bh[4], bl[4];
        #pragma unroll
        for (int f = 0; f < 4; ++f) {
            ah[f] = *(const bf16x8*)&sm[0][(wr * 4 + f) * 512 + l * 8];
            al[f] = *(const bf16x8*)&sm[1][(wr * 4 + f) * 512 + l * 8];
            bh[f] = *(const bf16x8*)&sm[2][(wc * 4 + f) * 512 + l * 8];
            bl[f] = *(const bf16x8*)&sm[3][(wc * 4 + f) * 512 + l * 8];
        }
        #pragma unroll
        for (int mf = 0; mf < 4; ++mf)
            #pragma unroll
            for (int nf = 0; nf < 4; ++nf) {
                acc[mf][nf] = __builtin_amdgcn_mfma_f32_16x16x32_bf16(
                    ah[mf], bh[nf], acc[mf][nf], 0, 0, 0);
                acc[mf][nf] = __builtin_amdgcn_mfma_f32_16x16x32_bf16(
                    ah[mf], bl[nf], acc[mf][nf], 0, 0, 0);
                acc[mf][nf] = __builtin_amdgcn_mfma_f32_16x16x32_bf16(
                    al[mf], bh[nf], acc[mf][nf], 0, 0, 0);
            }
    }

    // ---- DPP epilogue: per-row argmin, ZERO DS-pipe ops (R10/R12) ----
    // C/D layout (m89-verified): col = lane&15, row = (lane>>4)*4 + reg.
    const int g  = l >> 4;
    const int cc = l & 15;
    #pragma unroll
    for (int mf = 0; mf < 4; ++mf) {
        #pragma unroll
        for (int r = 0; r < 4; ++r) {
            float mm = fmaxf(-acc[mf][0][r], EPS_1);
            unsigned code = (unsigned)(c0 + wc * 64 + cc);
            #pragma unroll
            for (int nf = 1; nf < 4; ++nf) {
                float mv = fmaxf(-acc[mf][nf][r], EPS_1);
                if (mv < mm) { mm = mv; code = (unsigned)(c0 + wc * 64 + nf * 16 + cc); }
            }
            float mv = mm;
            DPP_MIN(mv, 0xB1);           // quad_perm xor1
            DPP_MIN(mv, 0x4E);           // quad_perm xor2
            DPP_MIN(mv, 0x141);          // row_half_mirror (8-group reversal)
            DPP_MIN(mv, 0x140);          // row_mirror (16-group reversal)
            if (mm == mv) {
                const int row = r0 + wr * 64 + mf * 16 + g * 4 + r;
                u64 key = ((u64)__float_as_uint(mm) << 32) | code;
                atomicMin(&keys[row], key);
            }
        }
    }

    // ---- fence-free level-1 handshake: last cbk-block gathers this rb ----
    int* sflagp = (int*)&sm[3][0];       // LDS overlay (staging done)
    __syncthreads();                     // drains vmcnt: key atomics in L2
    if (t == 0)
        *sflagp = (atomicAdd(&rb_done[rb], 1u) == 63u) ? 1 : 0;
    __syncthreads();
    if (!*sflagp) return;

    // keys for rows r0..r0+127 final: read via identity atomicMin RMW (L2)
    u64* smk = (u64*)&sm[0][0];          // 1 KB LDS reuse
    if (t < BMM)
        smk[t] = atomicMin(&keys[r0 + t], ~0ULL);
    __syncthreads();

    // gather: wave w handles rows w*32 .. w*32+31 (full 256-elem rows)
    float* zq = out + 1;
    float fsum = 0.f;
    for (int rr = 0; rr < 32; ++rr) {
        const int lrow = w * 32 + rr;
        const int row  = r0 + lrow;
        const int idx  = (int)(unsigned)(smk[lrow] & 0xffffffffULL);
        float4 uv = *(const float4*)&u[(size_t)row * D + l * 4];
        float4 cv = *(const float4*)&cb[(size_t)idx * D + l * 4];
        if (l == 0) uv.x = -uv.x;        // Lorentzian sign
        float partial = uv.x * cv.x + uv.y * cv.y + uv.z * cv.z + uv.w * cv.w;
        *(float4*)&zq[(size_t)row * D + l * 4] = cv;
        #pragma unroll
        for (int s = 32; s >= 1; s >>= 1)
            partial += __shfl_xor(partial, s);
        if (l == 0) {
            fsum += acoshf(fmaxf(-partial, EPS_1));
            atomicAdd(&counts[idx], 1.f);
        }
    }
    if (l == 0) atomicAdd(loss_sum, (double)fsum);

    // ---- fence-free level-2 handshake: last finisher does the scalars ----
    __syncthreads();                     // drains vmcnt: gather atomics in L2
    if (t == 0)
        *sflagp = (atomicAdd(gdone, 1u) == 63u) ? 1 : 0;
    __syncthreads();
    if (!*sflagp) return;

    // finalize: entropy / perplexity / e_mean / loss (atomic RMW reads, L2)
    float* red = (float*)&sm[1][0];      // 1 KB scratch, disjoint regions
    const int OFF_P = 1 + N_PTS * D;
    float ent = 0.f;
    for (int i = t; i < N_E; i += 256) {
        float cv_ = atomicAdd(&counts[i], 0.f);   // device-coherent read
        float e = cv_ * (1.0f / N_PTS);
        out[OFF_P + 2 + i] = e;
        ent -= e * logf(e + 1e-10f);
    }
    red[t] = ent;
    __syncthreads();
    for (int s = 128; s > 0; s >>= 1) {
        if (t < s) red[t] += red[t + s];
        __syncthreads();
    }
    if (t == 0) {
        float entropy = red[0];
        double ls = atomicAdd(loss_sum, 0.0);     // device-coherent read
        out[0]         = (1.0f + BETA) * (float)(ls / (double)N_PTS);
        out[OFF_P]     = expf(entropy);
        out[OFF_P + 1] = entropy;
    }
}

// ---------------- launch ----------------
extern "C" void kernel_launch(void* const* d_in, const int* in_sizes, int n_in,
                              void* d_out, int out_size, void* d_ws, size_t ws_size,
                              hipStream_t stream)
{
    const float* u  = (const float*)d_in[0];
    const float* cb = (const float*)d_in[1];
    float* out = (float*)d_out;
    char* ws = (char*)d_ws;

    u64*      keys     = (u64*)(ws + WS_KEYS);
    float*    counts   = (float*)(ws + WS_COUNTS);
    double*   loss_sum = (double*)(ws + WS_LOSS);
    unsigned* rb_done  = (unsigned*)(ws + WS_RB_DONE);
    unsigned* gdone    = (unsigned*)(ws + WS_GDONE);
    short*    Ahi = (short*)(ws + WS_AHI);
    short*    Alo = (short*)(ws + WS_ALO);
    short*    Bhi = (short*)(ws + WS_BHI);
    short*    Blo = (short*)(ws + WS_BLO);

    k_prep<<<N_PTS * D / 8 / 256, 256, 0, stream>>>(
        u, cb, Ahi, Alo, Bhi, Blo, keys, counts, loss_sum, rb_done, gdone);
    k_argmin_mfma<<<(N_PTS / BMM) * (N_E / BNN), 256, 0, stream>>>(
        Ahi, Alo, Bhi, Blo, keys, u, cb, out, counts, loss_sum, rb_done, gdone);
}

// Round 15
// 175.420 us; speedup vs baseline: 2.1507x; 1.0596x over previous
//
#include <hip/hip_runtime.h>
#include <hip/hip_bf16.h>
#include <stdint.h>

#define N_PTS   8192
#define D       256
#define N_E     8192
#define BETA    0.25f
#define EPS_1   1.0000001f   // 1 + 1e-7 (rounds to 1+ulp in f32, same as jnp)

typedef unsigned long long u64;
typedef __attribute__((ext_vector_type(8))) short bf16x8;   // 8 bf16 = 4 VGPR
typedef __attribute__((ext_vector_type(8))) short short8;
typedef __attribute__((ext_vector_type(4))) float f32x4;

// ---- workspace layout (bytes) ----
// Fragment-linear bf16 arrays for 16x16x32 MFMA (R2-R4 proven layout):
// element (p,k) of an 8192x256 matrix lives at
//   blk = (p>>4)*8 + (k>>5);  l = ((k>>3)&3)*16 + (p&15);  j = k&7
//   idx = blk*512 + l*8 + j
// Each 16x32 fragment is a contiguous 1KB block in lane-major order:
// global_load_lds(uniform base + lane*16) and ds_read_b128(lane*16) are both
// perfectly linear -> zero bank conflicts (verified R3-R14: conflicts = 0).
#define WS_KEYS    0
#define WS_COUNTS  (N_PTS * 8)                   // 64 KB
#define WS_LOSS    (WS_COUNTS + N_E * 4)         // +32 KB
#define WS_GDONE   (WS_LOSS + 16)                // u32
#define WS_AHI     (1 << 20)                     // 1 MB-aligned
#define WS_ALO     (WS_AHI + N_PTS * D * 2)
#define WS_BHI     (WS_ALO + N_PTS * D * 2)
#define WS_BLO     (WS_BHI + N_E * D * 2)        // total ~17 MB

__device__ __forceinline__ short f2bf(float x) {
    __hip_bfloat16 h = __float2bfloat16(x);      // RTN-even
    return *reinterpret_cast<short*>(&h);
}
__device__ __forceinline__ float bf2f(short s) {
    __hip_bfloat16 h = *reinterpret_cast<__hip_bfloat16*>(&s);
    return __bfloat162float(h);
}

#define GLOAD16(gp, lp) __builtin_amdgcn_global_load_lds(                      \
    (const __attribute__((address_space(1))) void*)(gp),                       \
    (__attribute__((address_space(3))) void*)(lp), 16, 0, 0)

// DPP f32 min step: x = min(x, x[dpp-perm(lane)]); pure VALU, no DS pipe.
// (validated on HW in R10/R12)
#define DPP_MIN(x, ctrl)                                                       \
    x = fminf(x, __int_as_float(__builtin_amdgcn_update_dpp(                   \
            __float_as_int(x), __float_as_int(x), (ctrl), 0xF, 0xF, true)))

// ------- init + split f32 -> bf16 hi/lo, fragment-linear layout -------------
__global__ __launch_bounds__(256) void k_prep(
    const float* __restrict__ u, const float* __restrict__ cb,
    short* __restrict__ Ahi, short* __restrict__ Alo,
    short* __restrict__ Bhi, short* __restrict__ Blo,
    u64* __restrict__ keys, float* __restrict__ counts,
    double* __restrict__ loss_sum, unsigned* __restrict__ gdone)
{
    const int tid = blockIdx.x * 256 + threadIdx.x;   // 0 .. 262143
    if (tid < N_E)   counts[tid] = 0.f;
    if (tid < N_PTS) keys[tid] = ~0ULL;
    if (tid == 0)  { *loss_sum = 0.0; *gdone = 0u; }

    const int blk = tid >> 6;            // = (p>>4)*8 + (k>>5)
    const int l   = tid & 63;
    const int s   = blk >> 3, c = blk & 7;
    const int p   = s * 16 + (l & 15);
    const int k   = c * 32 + (l >> 4) * 8;
    const size_t gin  = (size_t)p * D + k;
    const size_t gout = (size_t)tid * 8;

    float v[8];
    short8 h8, l8;

    *(float4*)&v[0] = *(const float4*)&u[gin];
    *(float4*)&v[4] = *(const float4*)&u[gin + 4];
    if (k == 0) v[0] = -v[0];            // Minkowski sign fold on time comp
    #pragma unroll
    for (int j = 0; j < 8; ++j) {
        h8[j] = f2bf(v[j]);
        l8[j] = f2bf(v[j] - bf2f(h8[j]));
    }
    *(short8*)&Ahi[gout] = h8;
    *(short8*)&Alo[gout] = l8;

    *(float4*)&v[0] = *(const float4*)&cb[gin];
    *(float4*)&v[4] = *(const float4*)&cb[gin + 4];
    #pragma unroll
    for (int j = 0; j < 8; ++j) {
        h8[j] = f2bf(v[j]);
        l8[j] = f2bf(v[j] - bf2f(h8[j]));
    }
    *(short8*)&Bhi[gout] = h8;
    *(short8*)&Blo[gout] = l8;
}

// ---------------- MFMA argmin: C = A~ . B^T, per-row argmin, no C write ------
// split-bf16: a.b = ahi.bhi + ahi.blo + alo.bhi  (err ~2^-18 rel, safe margin)
// EXACT R12 loop (measured optimum: 102 us argmin, FETCH 37 MB, 0 conflicts):
// 128x128 tile, 4 waves 2x2, 16x16x32 MFMA, 32 KB single-buffer LDS,
// 2 barriers/K-step, launch_bounds(256,4), natural block order, DPP epilogue.
// No setprio (R11: L2 thrash), no in-kernel fusion (R13/R14: regressed).
#define BMM 128
#define BNN 128
#define NKS (D / 32)         // 8 K-steps of 32

__global__ __launch_bounds__(256, 4) void k_argmin_mfma(
    const short* __restrict__ Ahi, const short* __restrict__ Alo,
    const short* __restrict__ Bhi, const short* __restrict__ Blo,
    u64* __restrict__ keys)
{
    __shared__ short sm[4][8 * 512];     // Ahi,Alo,Bhi,Blo: 8 KB each = 32 KB

    const int t   = threadIdx.x;
    const int w   = t >> 6;              // wave 0..3
    const int l   = t & 63;
    // natural order (R4-verified locality: FETCH 37 MB, L2-resident panels)
    const int rb  = blockIdx.x >> 6;     // 64 row-blocks (points)
    const int cbk = blockIdx.x & 63;     // 64 col-blocks (codes)
    const int r0  = rb * BMM, c0 = cbk * BNN;
    const int wr  = w >> 1, wc = w & 1;  // 2x2 wave grid, 64x64 each

    // staging: wave w owns one array; 8 fragment-blocks of 1KB per K-step
    const short* gsrc = (w == 0) ? Ahi : (w == 1) ? Alo : (w == 2) ? Bhi : Blo;
    short* ldst = sm[w];
    const int s0 = ((w < 2) ? rb : cbk) * 8;   // first 16-row slice index

    f32x4 acc[4][4];
    #pragma unroll
    for (int i = 0; i < 4; ++i)
        #pragma unroll
        for (int j = 0; j < 4; ++j) acc[i][j] = (f32x4){0.f, 0.f, 0.f, 0.f};

    for (int kk = 0; kk < NKS; ++kk) {
        __syncthreads();                 // prev compute done before overwrite
        #pragma unroll
        for (int i = 0; i < 8; ++i)
            GLOAD16(gsrc + (size_t)((s0 + i) * 8 + kk) * 512 + l * 8,
                    ldst + i * 512);
        __syncthreads();                 // drains vmcnt: tiles ready

        bf16x8 ah[4], al[4], bh[4], bl[4];
        #pragma unroll
        for (int f = 0; f < 4; ++f) {
            ah[f] = *(const bf16x8*)&sm[0][(wr * 4 + f) * 512 + l * 8];
            al[f] = *(const bf16x8*)&sm[1][(wr * 4 + f) * 512 + l * 8];
            bh[f] = *(const bf16x8*)&sm[2][(wc * 4 + f) * 512 + l * 8];
            bl[f] = *(const bf16x8*)&sm[3][(wc * 4 + f) * 512 + l * 8];
        }
        #pragma unroll
        for (int mf = 0; mf < 4; ++mf)
            #pragma unroll
            for (int nf = 0; nf < 4; ++nf) {
                acc[mf][nf] = __builtin_amdgcn_mfma_f32_16x16x32_bf16(
                    ah[mf], bh[nf], acc[mf][nf], 0, 0, 0);
                acc[mf][nf] = __builtin_amdgcn_mfma_f32_16x16x32_bf16(
                    ah[mf], bl[nf], acc[mf][nf], 0, 0, 0);
                acc[mf][nf] = __builtin_amdgcn_mfma_f32_16x16x32_bf16(
                    al[mf], bh[nf], acc[mf][nf], 0, 0, 0);
            }
    }

    // ---- DPP epilogue: per-row argmin, ZERO DS-pipe ops (R10/R12) ----
    // C/D layout (m89-verified): col = lane&15, row = (lane>>4)*4 + reg.
    const int g  = l >> 4;
    const int cc = l & 15;
    #pragma unroll
    for (int mf = 0; mf < 4; ++mf) {
        #pragma unroll
        for (int r = 0; r < 4; ++r) {
            float mm = fmaxf(-acc[mf][0][r], EPS_1);
            unsigned code = (unsigned)(c0 + wc * 64 + cc);
            #pragma unroll
            for (int nf = 1; nf < 4; ++nf) {
                float mv = fmaxf(-acc[mf][nf][r], EPS_1);
                if (mv < mm) { mm = mv; code = (unsigned)(c0 + wc * 64 + nf * 16 + cc); }
            }
            float mv = mm;
            DPP_MIN(mv, 0xB1);           // quad_perm xor1
            DPP_MIN(mv, 0x4E);           // quad_perm xor2
            DPP_MIN(mv, 0x141);          // row_half_mirror (8-group reversal)
            DPP_MIN(mv, 0x140);          // row_mirror (16-group reversal)
            if (mm == mv) {
                const int row = r0 + wr * 64 + mf * 16 + g * 4 + r;
                u64 key = ((u64)__float_as_uint(mm) << 32) | code;
                atomicMin(&keys[row], key);
            }
        }
    }
}

// ------- gather z_q, per-pair f32 distance, histogram (+fused finalize) -----
__global__ __launch_bounds__(256) void k_gather(
    const float* __restrict__ u, const float* __restrict__ cb,
    const u64* __restrict__ keys, float* __restrict__ out,
    float* __restrict__ counts, double* __restrict__ loss_sum,
    unsigned* __restrict__ gdone)
{
    __shared__ float sred[256];
    __shared__ int   sflag;
    const int t    = threadIdx.x;
    const int w    = t >> 6;
    const int row  = blockIdx.x * 4 + w;
    const int lane = t & 63;
    const u64 key  = keys[row];
    const int idx  = (int)(unsigned)(key & 0xffffffffULL);

    float* zq = out + 1;
    float4 uv = *(const float4*)&u[(size_t)row * D + lane * 4];
    float4 cv = *(const float4*)&cb[(size_t)idx * D + lane * 4];
    if (lane == 0) uv.x = -uv.x;                  // Lorentzian sign
    float partial = uv.x * cv.x + uv.y * cv.y + uv.z * cv.z + uv.w * cv.w;
    *(float4*)&zq[(size_t)row * D + lane * 4] = cv;

    #pragma unroll
    for (int s = 32; s >= 1; s >>= 1)
        partial += __shfl_xor(partial, s);

    if (lane == 0) {
        float m = fmaxf(-partial, EPS_1);
        sred[w] = acoshf(m);
        atomicAdd(&counts[idx], 1.f);             // scattered: low contention
    }
    __syncthreads();
    if (t == 0)                                   // 1 f64 atomic per block
        atomicAdd(loss_sum, (double)(sred[0] + sred[1] + sred[2] + sred[3]));

    // ---- fence-free last-block finalize (handshake validated R13/R14):
    // syncthreads drains vmcnt(0) per wave BEFORE the gdone atomic issues,
    // so this block's counts/loss atomics are acked in L2 first. All
    // cross-block reads below are atomic RMWs (L2-coherent, L1-bypassing).
    __syncthreads();
    if (t == 0)
        sflag = (atomicAdd(gdone, 1u) == (unsigned)(N_PTS / 4 - 1)) ? 1 : 0;
    __syncthreads();
    if (!sflag) return;

    const int OFF_P = 1 + N_PTS * D;
    float ent = 0.f;
    for (int i = t; i < N_E; i += 256) {
        float cv_ = atomicAdd(&counts[i], 0.f);   // device-coherent read
        float e = cv_ * (1.0f / N_PTS);
        out[OFF_P + 2 + i] = e;
        ent -= e * logf(e + 1e-10f);
    }
    sred[t] = ent;
    __syncthreads();
    for (int s = 128; s > 0; s >>= 1) {
        if (t < s) sred[t] += sred[t + s];
        __syncthreads();
    }
    if (t == 0) {
        float entropy = sred[0];
        double ls = atomicAdd(loss_sum, 0.0);     // device-coherent read
        out[0]         = (1.0f + BETA) * (float)(ls / (double)N_PTS);
        out[OFF_P]     = expf(entropy);
        out[OFF_P + 1] = entropy;
    }
}

// ---------------- launch ----------------
extern "C" void kernel_launch(void* const* d_in, const int* in_sizes, int n_in,
                              void* d_out, int out_size, void* d_ws, size_t ws_size,
                              hipStream_t stream)
{
    const float* u  = (const float*)d_in[0];
    const float* cb = (const float*)d_in[1];
    float* out = (float*)d_out;
    char* ws = (char*)d_ws;

    u64*      keys     = (u64*)(ws + WS_KEYS);
    float*    counts   = (float*)(ws + WS_COUNTS);
    double*   loss_sum = (double*)(ws + WS_LOSS);
    unsigned* gdone    = (unsigned*)(ws + WS_GDONE);
    short*    Ahi = (short*)(ws + WS_AHI);
    short*    Alo = (short*)(ws + WS_ALO);
    short*    Bhi = (short*)(ws + WS_BHI);
    short*    Blo = (short*)(ws + WS_BLO);

    k_prep<<<N_PTS * D / 8 / 256, 256, 0, stream>>>(
        u, cb, Ahi, Alo, Bhi, Blo, keys, counts, loss_sum, gdone);
    k_argmin_mfma<<<(N_PTS / BMM) * (N_E / BNN), 256, 0, stream>>>(
        Ahi, Alo, Bhi, Blo, keys);
    k_gather<<<N_PTS / 4, 256, 0, stream>>>(
        u, cb, keys, out, counts, loss_sum, gdone);
}

// Round 16
// 169.386 us; speedup vs baseline: 2.2273x; 1.0356x over previous
//
#include <hip/hip_runtime.h>
#include <hip/hip_bf16.h>
#include <stdint.h>

#define N_PTS   8192
#define D       256
#define N_E     8192
#define BETA    0.25f
#define EPS_1   1.0000001f   // 1 + 1e-7 (rounds to 1+ulp in f32, same as jnp)

typedef unsigned long long u64;
typedef __attribute__((ext_vector_type(8)))  short bf16x8;   // 8 bf16 = 4 VGPR
typedef __attribute__((ext_vector_type(8)))  short short8;
typedef __attribute__((ext_vector_type(16))) float f32x16;

// ---- workspace layout (bytes) ----
// Fragment-linear bf16 arrays for 32x32x16 MFMA (R5-R9 validated layout):
// element (p,k) of an 8192x256 matrix lives at
//   fi = (p>>5)*16 + (k>>4);  l = (p&31) + 32*((k&15)>>3);  j = k&7
//   idx = fi*512 + l*8 + j
// Each 32x16 fragment is a contiguous 1KB block in lane-major order:
// global_load_lds(uniform base + lane*16) and ds_read_b128(lane*16) are both
// perfectly linear -> zero bank conflicts (verified R3-R15: conflicts = 0).
#define WS_KEYS   0
#define WS_COUNTS (N_PTS * 8)                    // 64 KB
#define WS_LOSS   (WS_COUNTS + N_E * 4)          // +32 KB
#define WS_AHI    (1 << 20)                      // 1 MB-aligned
#define WS_ALO    (WS_AHI + N_PTS * D * 2)
#define WS_BHI    (WS_ALO + N_PTS * D * 2)
#define WS_BLO    (WS_BHI + N_E * D * 2)         // total ~17 MB

__device__ __forceinline__ short f2bf(float x) {
    __hip_bfloat16 h = __float2bfloat16(x);      // RTN-even
    return *reinterpret_cast<short*>(&h);
}
__device__ __forceinline__ float bf2f(short s) {
    __hip_bfloat16 h = *reinterpret_cast<__hip_bfloat16*>(&s);
    return __bfloat162float(h);
}

#define GLOAD16(gp, lp) __builtin_amdgcn_global_load_lds(                      \
    (const __attribute__((address_space(1))) void*)(gp),                       \
    (__attribute__((address_space(3))) void*)(lp), 16, 0, 0)

// DPP f32 min step: x = min(x, x[dpp-perm(lane)]); pure VALU, no DS pipe.
// (validated on HW in R10/R12)
#define DPP_MIN(x, ctrl)                                                       \
    x = fminf(x, __int_as_float(__builtin_amdgcn_update_dpp(                   \
            __float_as_int(x), __float_as_int(x), (ctrl), 0xF, 0xF, true)))

// ------- init + split f32 -> bf16 hi/lo, fragment-linear (32x16 frags) ------
__global__ __launch_bounds__(256) void k_prep(
    const float* __restrict__ u, const float* __restrict__ cb,
    short* __restrict__ Ahi, short* __restrict__ Alo,
    short* __restrict__ Bhi, short* __restrict__ Blo,
    u64* __restrict__ keys, float* __restrict__ counts,
    double* __restrict__ loss_sum)
{
    const int tid = blockIdx.x * 256 + threadIdx.x;   // 0 .. 262143
    if (tid < N_E)   counts[tid] = 0.f;
    if (tid < N_PTS) keys[tid] = ~0ULL;
    if (tid == 0)    *loss_sum = 0.0;

    const int fi = tid >> 6;             // fragment index (p>>5)*16 + (k>>4)
    const int l  = tid & 63;
    const int p  = (fi >> 4) * 32 + (l & 31);
    const int k  = (fi & 15) * 16 + (l >> 5) * 8;
    const size_t gin  = (size_t)p * D + k;
    const size_t gout = (size_t)tid * 8;

    float v[8];
    short8 h8, l8;

    *(float4*)&v[0] = *(const float4*)&u[gin];
    *(float4*)&v[4] = *(const float4*)&u[gin + 4];
    if (k == 0) v[0] = -v[0];            // Minkowski sign fold on time comp
    #pragma unroll
    for (int j = 0; j < 8; ++j) {
        h8[j] = f2bf(v[j]);
        l8[j] = f2bf(v[j] - bf2f(h8[j]));
    }
    *(short8*)&Ahi[gout] = h8;
    *(short8*)&Alo[gout] = l8;

    *(float4*)&v[0] = *(const float4*)&cb[gin];
    *(float4*)&v[4] = *(const float4*)&cb[gin + 4];
    #pragma unroll
    for (int j = 0; j < 8; ++j) {
        h8[j] = f2bf(v[j]);
        l8[j] = f2bf(v[j] - bf2f(h8[j]));
    }
    *(short8*)&Bhi[gout] = h8;
    *(short8*)&Blo[gout] = l8;
}

// ---------------- MFMA argmin: C = A~ . B^T, per-row argmin, no C write ------
// split-bf16: a.b = ahi.bhi + ahi.blo + alo.bhi  (err ~2^-18 rel, safe margin)
// R12 structure (measured optimum; 5 restructures R5-R9 + 2 fusions R13-R15
// all regressed): 128x128 tile, 4 waves 2x2 of 64x64, 32 KB single-buffer
// LDS, 2 barriers/K-step, launch_bounds(256,4), natural order, DPP epilogue.
// R16 single-variable change: MFMA shape 16x16x32 -> 32x32x16 (m119: 2495 vs
// 2075 TF ceiling; halves MFMA instruction count -> MFMA pipe term 50->41 us
// and frees issue slots for the ds_read interleave). Layout R5-R9-validated.
#define BMM 128
#define BNN 128
#define NKS (D / 32)         // 8 K-steps of 32 (= 2 fragment-columns each)

__global__ __launch_bounds__(256, 4) void k_argmin_mfma(
    const short* __restrict__ Ahi, const short* __restrict__ Alo,
    const short* __restrict__ Bhi, const short* __restrict__ Blo,
    u64* __restrict__ keys)
{
    __shared__ short sm[4][8 * 512];     // Ahi,Alo,Bhi,Blo: 8 KB each = 32 KB

    const int t   = threadIdx.x;
    const int w   = t >> 6;              // wave 0..3
    const int l   = t & 63;
    // natural order (R4-verified locality: FETCH 37 MB, L2-resident panels)
    const int rb  = blockIdx.x >> 6;     // 64 row-blocks (points)
    const int cbk = blockIdx.x & 63;     // 64 col-blocks (codes)
    const int r0  = rb * BMM, c0 = cbk * BNN;
    const int wr  = w >> 1, wc = w & 1;  // 2x2 wave grid, 64x64 each

    // staging: wave w owns one array; 8 fragments (4 row x 2 k) per K-step
    const short* gsrc = (w == 0) ? Ahi : (w == 1) ? Alo : (w == 2) ? Bhi : Blo;
    short* ldst = sm[w];
    const int eb = ((w < 2) ? rb : cbk) * 4;   // entity fragment-row base

    f32x16 acc[2][2];
    #pragma unroll
    for (int i = 0; i < 2; ++i)
        #pragma unroll
        for (int j = 0; j < 2; ++j)
            #pragma unroll
            for (int r = 0; r < 16; ++r) acc[i][j][r] = 0.f;

    for (int kk = 0; kk < NKS; ++kk) {
        __syncthreads();                 // prev compute done before overwrite
        #pragma unroll
        for (int i = 0; i < 8; ++i) {
            const int rf = i >> 1, kf = i & 1;
            GLOAD16(gsrc + ((size_t)(eb + rf) * 16 + kk * 2 + kf) * 512 + l * 8,
                    ldst + (rf * 2 + kf) * 512);
        }
        __syncthreads();                 // drains vmcnt: tiles ready

        #pragma unroll
        for (int kf = 0; kf < 2; ++kf) {
            bf16x8 ah[2], al[2], bh[2], bl[2];
            #pragma unroll
            for (int m = 0; m < 2; ++m) {
                ah[m] = *(const bf16x8*)&sm[0][((wr * 2 + m) * 2 + kf) * 512 + l * 8];
                al[m] = *(const bf16x8*)&sm[1][((wr * 2 + m) * 2 + kf) * 512 + l * 8];
                bh[m] = *(const bf16x8*)&sm[2][((wc * 2 + m) * 2 + kf) * 512 + l * 8];
                bl[m] = *(const bf16x8*)&sm[3][((wc * 2 + m) * 2 + kf) * 512 + l * 8];
            }
            // same-acc MFMAs spaced 4 apart (>= issue latency of 32x32)
            #pragma unroll
            for (int m = 0; m < 2; ++m)
                #pragma unroll
                for (int n = 0; n < 2; ++n)
                    acc[m][n] = __builtin_amdgcn_mfma_f32_32x32x16_bf16(
                        ah[m], bh[n], acc[m][n], 0, 0, 0);
            #pragma unroll
            for (int m = 0; m < 2; ++m)
                #pragma unroll
                for (int n = 0; n < 2; ++n)
                    acc[m][n] = __builtin_amdgcn_mfma_f32_32x32x16_bf16(
                        ah[m], bl[n], acc[m][n], 0, 0, 0);
            #pragma unroll
            for (int m = 0; m < 2; ++m)
                #pragma unroll
                for (int n = 0; n < 2; ++n)
                    acc[m][n] = __builtin_amdgcn_mfma_f32_32x32x16_bf16(
                        al[m], bh[n], acc[m][n], 0, 0, 0);
        }
    }

    // ---- DPP epilogue: per-row argmin, ZERO DS-pipe ops (R10-validated) ----
    // 32x32 C/D layout (m74/m101-verified):
    //   col = lane&31, row = (reg&3) + 8*(reg>>2) + 4*(lane>>5)
    // In-lane min across n (strict < keeps lower code = np.argmin), f32
    // value-min across the 32 col-lanes via 4 DPP + 1 shfl_xor(16); every
    // lane holding the row-min fires the u64 atomicMin (ties resolved by
    // (value,code) key order exactly).
    const int ch = l & 31;
    #pragma unroll
    for (int m = 0; m < 2; ++m) {
        const int rowbase = r0 + wr * 64 + m * 32 + 4 * (l >> 5);
        #pragma unroll
        for (int r = 0; r < 16; ++r) {
            float m0 = fmaxf(-acc[m][0][r], EPS_1);
            float m1 = fmaxf(-acc[m][1][r], EPS_1);
            float mm = fminf(m0, m1);
            unsigned code = (unsigned)(c0 + wc * 64 + (m1 < m0 ? 32 : 0) + ch);
            float mv = mm;
            DPP_MIN(mv, 0xB1);           // quad_perm xor1
            DPP_MIN(mv, 0x4E);           // quad_perm xor2
            DPP_MIN(mv, 0x141);          // row_half_mirror (8-group reversal)
            DPP_MIN(mv, 0x140);          // row_mirror (16-group reversal)
            mv = fminf(mv, __shfl_xor(mv, 16));   // cross-16 within 32 lanes
            if (mm == mv) {
                const int row = rowbase + (r & 3) + 8 * (r >> 2);
                u64 key = ((u64)__float_as_uint(mm) << 32) | code;
                atomicMin(&keys[row], key);
            }
        }
    }
}

// ---------------- gather z_q, per-pair f32 distance, histogram ----------------
__global__ __launch_bounds__(256) void k_gather(
    const float* __restrict__ u, const float* __restrict__ cb,
    const u64* __restrict__ keys, float* __restrict__ out,
    float* __restrict__ counts, double* __restrict__ loss_sum)
{
    __shared__ float sred[4];
    const int t    = threadIdx.x;
    const int w    = t >> 6;
    const int row  = blockIdx.x * 4 + w;
    const int lane = t & 63;
    const u64 key  = keys[row];
    const int idx  = (int)(unsigned)(key & 0xffffffffULL);

    float* zq = out + 1;
    float4 uv = *(const float4*)&u[(size_t)row * D + lane * 4];
    float4 cv = *(const float4*)&cb[(size_t)idx * D + lane * 4];
    if (lane == 0) uv.x = -uv.x;                  // Lorentzian sign
    float partial = uv.x * cv.x + uv.y * cv.y + uv.z * cv.z + uv.w * cv.w;
    *(float4*)&zq[(size_t)row * D + lane * 4] = cv;

    #pragma unroll
    for (int s = 32; s >= 1; s >>= 1)
        partial += __shfl_xor(partial, s);

    if (lane == 0) {
        float m = fmaxf(-partial, EPS_1);
        sred[w] = acoshf(m);
        atomicAdd(&counts[idx], 1.f);             // scattered: low contention
    }
    __syncthreads();
    if (t == 0)                                   // 1 f64 atomic per block
        atomicAdd(loss_sum, (double)(sred[0] + sred[1] + sred[2] + sred[3]));
}

// ---------------- scalars: loss, perplexity, entropy, e_mean -----------------
__global__ __launch_bounds__(256) void k_final(
    const float* __restrict__ counts, const double* __restrict__ loss_sum,
    float* __restrict__ out)
{
    __shared__ float red[256];
    const int t = threadIdx.x;
    const int OFF_P = 1 + N_PTS * D;
    float ent = 0.f;
    for (int i = t; i < N_E; i += 256) {
        float e = counts[i] * (1.0f / N_PTS);
        out[OFF_P + 2 + i] = e;
        ent -= e * logf(e + 1e-10f);
    }
    red[t] = ent;
    __syncthreads();
    for (int s = 128; s > 0; s >>= 1) {
        if (t < s) red[t] += red[t + s];
        __syncthreads();
    }
    if (t == 0) {
        float entropy = red[0];
        out[0]         = (1.0f + BETA) * (float)(*loss_sum / (double)N_PTS);
        out[OFF_P]     = expf(entropy);
        out[OFF_P + 1] = entropy;
    }
}

// ---------------- launch ----------------
extern "C" void kernel_launch(void* const* d_in, const int* in_sizes, int n_in,
                              void* d_out, int out_size, void* d_ws, size_t ws_size,
                              hipStream_t stream)
{
    const float* u  = (const float*)d_in[0];
    const float* cb = (const float*)d_in[1];
    float* out = (float*)d_out;
    char* ws = (char*)d_ws;

    u64*    keys     = (u64*)(ws + WS_KEYS);
    float*  counts   = (float*)(ws + WS_COUNTS);
    double* loss_sum = (double*)(ws + WS_LOSS);
    short*  Ahi = (short*)(ws + WS_AHI);
    short*  Alo = (short*)(ws + WS_ALO);
    short*  Bhi = (short*)(ws + WS_BHI);
    short*  Blo = (short*)(ws + WS_BLO);

    k_prep<<<N_PTS * D / 8 / 256, 256, 0, stream>>>(u, cb, Ahi, Alo, Bhi, Blo,
                                                    keys, counts, loss_sum);
    k_argmin_mfma<<<(N_PTS / BMM) * (N_E / BNN), 256, 0, stream>>>(
        Ahi, Alo, Bhi, Blo, keys);
    k_gather<<<N_PTS / 4, 256, 0, stream>>>(u, cb, keys, out, counts, loss_sum);
    k_final<<<1, 256, 0, stream>>>(counts, loss_sum, out);
}

// Round 17
// 150.558 us; speedup vs baseline: 2.5058x; 1.1251x over previous
//
#include <hip/hip_runtime.h>
#include <hip/hip_bf16.h>
#include <stdint.h>

#define N_PTS   8192
#define D       256
#define N_E     8192
#define BETA    0.25f
#define EPS_1   1.0000001f   // 1 + 1e-7 (rounds to 1+ulp in f32, same as jnp)

typedef unsigned long long u64;
typedef __attribute__((ext_vector_type(8))) short bf16x8;   // 8 bf16 = 4 VGPR
typedef __attribute__((ext_vector_type(8))) short short8;
typedef __attribute__((ext_vector_type(4))) float f32x4;

// ---- workspace layout (bytes) ----
// Fragment-linear bf16 arrays for 16x16x32 MFMA (R2-R4 proven layout):
// element (p,k) of an 8192x256 matrix lives at
//   blk = (p>>4)*8 + (k>>5);  l = ((k>>3)&3)*16 + (p&15);  j = k&7
//   idx = blk*512 + l*8 + j
// Each 16x32 fragment is a contiguous 1KB block in lane-major order:
// global_load_lds(uniform base + lane*16) and ds_read_b128(lane*16) are both
// perfectly linear -> zero bank conflicts (verified R3-R16: conflicts = 0).
#define WS_KEYS   0
#define WS_COUNTS (N_PTS * 8)                    // 64 KB
#define WS_LOSS   (WS_COUNTS + N_E * 4)          // +32 KB
#define WS_AHI    (1 << 20)                      // 1 MB-aligned
#define WS_ALO    (WS_AHI + N_PTS * D * 2)
#define WS_BHI    (WS_ALO + N_PTS * D * 2)
#define WS_BLO    (WS_BHI + N_E * D * 2)         // total ~17 MB

__device__ __forceinline__ short f2bf(float x) {
    __hip_bfloat16 h = __float2bfloat16(x);      // RTN-even
    return *reinterpret_cast<short*>(&h);
}
__device__ __forceinline__ float bf2f(short s) {
    __hip_bfloat16 h = *reinterpret_cast<__hip_bfloat16*>(&s);
    return __bfloat162float(h);
}

#define GLOAD16(gp, lp) __builtin_amdgcn_global_load_lds(                      \
    (const __attribute__((address_space(1))) void*)(gp),                       \
    (__attribute__((address_space(3))) void*)(lp), 16, 0, 0)

// DPP f32 min step: x = min(x, x[dpp-perm(lane)]); pure VALU, no DS pipe.
// (validated on HW in R10/R12)
#define DPP_MIN(x, ctrl)                                                       \
    x = fminf(x, __int_as_float(__builtin_amdgcn_update_dpp(                   \
            __float_as_int(x), __float_as_int(x), (ctrl), 0xF, 0xF, true)))

// ------- init + split f32 -> bf16 hi/lo, fragment-linear layout -------------
__global__ __launch_bounds__(256) void k_prep(
    const float* __restrict__ u, const float* __restrict__ cb,
    short* __restrict__ Ahi, short* __restrict__ Alo,
    short* __restrict__ Bhi, short* __restrict__ Blo,
    u64* __restrict__ keys, float* __restrict__ counts,
    double* __restrict__ loss_sum)
{
    const int tid = blockIdx.x * 256 + threadIdx.x;   // 0 .. 262143
    if (tid < N_E)   counts[tid] = 0.f;
    if (tid < N_PTS) keys[tid] = ~0ULL;
    if (tid == 0)    *loss_sum = 0.0;

    const int blk = tid >> 6;            // = (p>>4)*8 + (k>>5)
    const int l   = tid & 63;
    const int s   = blk >> 3, c = blk & 7;
    const int p   = s * 16 + (l & 15);
    const int k   = c * 32 + (l >> 4) * 8;
    const size_t gin  = (size_t)p * D + k;
    const size_t gout = (size_t)tid * 8;

    float v[8];
    short8 h8, l8;

    *(float4*)&v[0] = *(const float4*)&u[gin];
    *(float4*)&v[4] = *(const float4*)&u[gin + 4];
    if (k == 0) v[0] = -v[0];            // Minkowski sign fold on time comp
    #pragma unroll
    for (int j = 0; j < 8; ++j) {
        h8[j] = f2bf(v[j]);
        l8[j] = f2bf(v[j] - bf2f(h8[j]));
    }
    *(short8*)&Ahi[gout] = h8;
    *(short8*)&Alo[gout] = l8;

    *(float4*)&v[0] = *(const float4*)&cb[gin];
    *(float4*)&v[4] = *(const float4*)&cb[gin + 4];
    #pragma unroll
    for (int j = 0; j < 8; ++j) {
        h8[j] = f2bf(v[j]);
        l8[j] = f2bf(v[j] - bf2f(h8[j]));
    }
    *(short8*)&Bhi[gout] = h8;
    *(short8*)&Blo[gout] = l8;
}

// ---------------- MFMA argmin: C = A~ . B^T, per-row argmin, no C write ------
// split-bf16: a.b = ahi.bhi + ahi.blo + alo.bhi  (err ~2^-18 rel, safe margin)
// EXACT R12 configuration -- the measured optimum across 16 rounds:
// 128x128 tile, 4 waves 2x2, 16x16x32 MFMA, 32 KB single-buffer LDS,
// 2 barriers/K-step, launch_bounds(256,4), natural block order, DPP epilogue.
// Evidence this is a sharp local optimum (one variable changed per round):
//   R16 32x32x16 shape: 102->128 us (staging-bound, not MFMA-bound)
//   R11 +setprio:       L2 thrash, FETCH 37->210 MB
//   R9  256^2 tile:     occupancy 37->22%, slower
//   R5-R8 deep pipelines: all ~200 us (barrier-drain dominated)
//   R13-R15 fusions:    all regressed (finisher serialization)
#define BMM 128
#define BNN 128
#define NKS (D / 32)         // 8 K-steps of 32

__global__ __launch_bounds__(256, 4) void k_argmin_mfma(
    const short* __restrict__ Ahi, const short* __restrict__ Alo,
    const short* __restrict__ Bhi, const short* __restrict__ Blo,
    u64* __restrict__ keys)
{
    __shared__ short sm[4][8 * 512];     // Ahi,Alo,Bhi,Blo: 8 KB each = 32 KB

    const int t   = threadIdx.x;
    const int w   = t >> 6;              // wave 0..3
    const int l   = t & 63;
    // natural order (R4-verified locality: FETCH 37 MB, L2-resident panels)
    const int rb  = blockIdx.x >> 6;     // 64 row-blocks (points)
    const int cbk = blockIdx.x & 63;     // 64 col-blocks (codes)
    const int r0  = rb * BMM, c0 = cbk * BNN;
    const int wr  = w >> 1, wc = w & 1;  // 2x2 wave grid, 64x64 each

    // staging: wave w owns one array; 8 fragment-blocks of 1KB per K-step
    const short* gsrc = (w == 0) ? Ahi : (w == 1) ? Alo : (w == 2) ? Bhi : Blo;
    short* ldst = sm[w];
    const int s0 = ((w < 2) ? rb : cbk) * 8;   // first 16-row slice index

    f32x4 acc[4][4];
    #pragma unroll
    for (int i = 0; i < 4; ++i)
        #pragma unroll
        for (int j = 0; j < 4; ++j) acc[i][j] = (f32x4){0.f, 0.f, 0.f, 0.f};

    for (int kk = 0; kk < NKS; ++kk) {
        __syncthreads();                 // prev compute done before overwrite
        #pragma unroll
        for (int i = 0; i < 8; ++i)
            GLOAD16(gsrc + (size_t)((s0 + i) * 8 + kk) * 512 + l * 8,
                    ldst + i * 512);
        __syncthreads();                 // drains vmcnt: tiles ready

        bf16x8 ah[4], al[4], bh[4], bl[4];
        #pragma unroll
        for (int f = 0; f < 4; ++f) {
            ah[f] = *(const bf16x8*)&sm[0][(wr * 4 + f) * 512 + l * 8];
            al[f] = *(const bf16x8*)&sm[1][(wr * 4 + f) * 512 + l * 8];
            bh[f] = *(const bf16x8*)&sm[2][(wc * 4 + f) * 512 + l * 8];
            bl[f] = *(const bf16x8*)&sm[3][(wc * 4 + f) * 512 + l * 8];
        }
        #pragma unroll
        for (int mf = 0; mf < 4; ++mf)
            #pragma unroll
            for (int nf = 0; nf < 4; ++nf) {
                acc[mf][nf] = __builtin_amdgcn_mfma_f32_16x16x32_bf16(
                    ah[mf], bh[nf], acc[mf][nf], 0, 0, 0);
                acc[mf][nf] = __builtin_amdgcn_mfma_f32_16x16x32_bf16(
                    ah[mf], bl[nf], acc[mf][nf], 0, 0, 0);
                acc[mf][nf] = __builtin_amdgcn_mfma_f32_16x16x32_bf16(
                    al[mf], bh[nf], acc[mf][nf], 0, 0, 0);
            }
    }

    // ---- DPP epilogue: per-row argmin, ZERO DS-pipe ops (R10/R12) ----
    // C/D layout (m89-verified): col = lane&15, row = (lane>>4)*4 + reg.
    const int g  = l >> 4;
    const int cc = l & 15;
    #pragma unroll
    for (int mf = 0; mf < 4; ++mf) {
        #pragma unroll
        for (int r = 0; r < 4; ++r) {
            float mm = fmaxf(-acc[mf][0][r], EPS_1);
            unsigned code = (unsigned)(c0 + wc * 64 + cc);
            #pragma unroll
            for (int nf = 1; nf < 4; ++nf) {
                float mv = fmaxf(-acc[mf][nf][r], EPS_1);
                if (mv < mm) { mm = mv; code = (unsigned)(c0 + wc * 64 + nf * 16 + cc); }
            }
            float mv = mm;
            DPP_MIN(mv, 0xB1);           // quad_perm xor1
            DPP_MIN(mv, 0x4E);           // quad_perm xor2
            DPP_MIN(mv, 0x141);          // row_half_mirror (8-group reversal)
            DPP_MIN(mv, 0x140);          // row_mirror (16-group reversal)
            if (mm == mv) {
                const int row = r0 + wr * 64 + mf * 16 + g * 4 + r;
                u64 key = ((u64)__float_as_uint(mm) << 32) | code;
                atomicMin(&keys[row], key);
            }
        }
    }
}

// ---------------- gather z_q, per-pair f32 distance, histogram ----------------
__global__ __launch_bounds__(256) void k_gather(
    const float* __restrict__ u, const float* __restrict__ cb,
    const u64* __restrict__ keys, float* __restrict__ out,
    float* __restrict__ counts, double* __restrict__ loss_sum)
{
    __shared__ float sred[4];
    const int t    = threadIdx.x;
    const int w    = t >> 6;
    const int row  = blockIdx.x * 4 + w;
    const int lane = t & 63;
    const u64 key  = keys[row];
    const int idx  = (int)(unsigned)(key & 0xffffffffULL);

    float* zq = out + 1;
    float4 uv = *(const float4*)&u[(size_t)row * D + lane * 4];
    float4 cv = *(const float4*)&cb[(size_t)idx * D + lane * 4];
    if (lane == 0) uv.x = -uv.x;                  // Lorentzian sign
    float partial = uv.x * cv.x + uv.y * cv.y + uv.z * cv.z + uv.w * cv.w;
    *(float4*)&zq[(size_t)row * D + lane * 4] = cv;

    #pragma unroll
    for (int s = 32; s >= 1; s >>= 1)
        partial += __shfl_xor(partial, s);

    if (lane == 0) {
        float m = fmaxf(-partial, EPS_1);
        sred[w] = acoshf(m);
        atomicAdd(&counts[idx], 1.f);             // scattered: low contention
    }
    __syncthreads();
    if (t == 0)                                   // 1 f64 atomic per block
        atomicAdd(loss_sum, (double)(sred[0] + sred[1] + sred[2] + sred[3]));
}

// ---------------- scalars: loss, perplexity, entropy, e_mean -----------------
__global__ __launch_bounds__(256) void k_final(
    const float* __restrict__ counts, const double* __restrict__ loss_sum,
    float* __restrict__ out)
{
    __shared__ float red[256];
    const int t = threadIdx.x;
    const int OFF_P = 1 + N_PTS * D;
    float ent = 0.f;
    for (int i = t; i < N_E; i += 256) {
        float e = counts[i] * (1.0f / N_PTS);
        out[OFF_P + 2 + i] = e;
        ent -= e * logf(e + 1e-10f);
    }
    red[t] = ent;
    __syncthreads();
    for (int s = 128; s > 0; s >>= 1) {
        if (t < s) red[t] += red[t + s];
        __syncthreads();
    }
    if (t == 0) {
        float entropy = red[0];
        out[0]         = (1.0f + BETA) * (float)(*loss_sum / (double)N_PTS);
        out[OFF_P]     = expf(entropy);
        out[OFF_P + 1] = entropy;
    }
}

// ---------------- launch ----------------
extern "C" void kernel_launch(void* const* d_in, const int* in_sizes, int n_in,
                              void* d_out, int out_size, void* d_ws, size_t ws_size,
                              hipStream_t stream)
{
    const float* u  = (const float*)d_in[0];
    const float* cb = (const float*)d_in[1];
    float* out = (float*)d_out;
    char* ws = (char*)d_ws;

    u64*    keys     = (u64*)(ws + WS_KEYS);
    float*  counts   = (float*)(ws + WS_COUNTS);
    double* loss_sum = (double*)(ws + WS_LOSS);
    short*  Ahi = (short*)(ws + WS_AHI);
    short*  Alo = (short*)(ws + WS_ALO);
    short*  Bhi = (short*)(ws + WS_BHI);
    short*  Blo = (short*)(ws + WS_BLO);

    k_prep<<<N_PTS * D / 8 / 256, 256, 0, stream>>>(u, cb, Ahi, Alo, Bhi, Blo,
                                                    keys, counts, loss_sum);
    k_argmin_mfma<<<(N_PTS / BMM) * (N_E / BNN), 256, 0, stream>>>(
        Ahi, Alo, Bhi, Blo, keys);
    k_gather<<<N_PTS / 4, 256, 0, stream>>>(u, cb, keys, out, counts, loss_sum);
    k_final<<<1, 256, 0, stream>>>(counts, loss_sum, out);
}